// Round 1
// baseline (55.122 us; speedup 1.0000x reference)
//
#include <hip/hip_runtime.h>
#include <cmath>

#define NHEADS 8
#define HDIM 128
#define SPAN 24
#define U_ 16
#define W_ 128
#define C_ 151
#define HID 1024

typedef unsigned short ushort8v __attribute__((ext_vector_type(8)));
typedef __bf16 bf16x8 __attribute__((ext_vector_type(8)));
typedef float f32x4 __attribute__((ext_vector_type(4)));

__device__ inline unsigned short f2bf(float f) {
    union { float f; unsigned u; } v; v.f = f;
    unsigned r = v.u + 0x7FFFu + ((v.u >> 16) & 1u);
    return (unsigned short)(r >> 16);
}

// ---- kernel 1: partial column sums of pos_proj (64 blocks x 16 rows) ----
__global__ void k_partial(const float* __restrict__ pp, float* __restrict__ part) {
    const int t = threadIdx.x;            // 256 threads, each 4 cols (float4)
    const int row0 = blockIdx.x * 16;
    float4 s = make_float4(0.f, 0.f, 0.f, 0.f);
    #pragma unroll
    for (int i = 0; i < 16; ++i) {
        float4 v = *(const float4*)(pp + (size_t)(row0 + i) * HID + t * 4);
        s.x += v.x; s.y += v.y; s.z += v.z; s.w += v.w;
    }
    *(float4*)(part + (size_t)blockIdx.x * HID + t * 4) = s;
}

// ---- kernel 2: reduce partials, emit bf16 embedding table [24][1024] ----
struct SC { float s[SPAN]; float c[SPAN]; };

__global__ void k_emb(const float* __restrict__ part, unsigned short* __restrict__ emb, SC sc) {
    const int j = blockIdx.x * 256 + threadIdx.x;   // 0..1023
    float s1 = 0.f, s2 = 0.f;
    #pragma unroll 4
    for (int i = 0; i < 32; ++i) s1 += part[(size_t)i * HID + j];
    #pragma unroll 4
    for (int i = 32; i < 64; ++i) s2 += part[(size_t)i * HID + j];
    #pragma unroll
    for (int f = 0; f < SPAN; ++f)
        emb[(size_t)f * HID + j] = f2bf(sc.s[f] * s1 + sc.c[f] * s2);
}

// ---- main kernel: per-(b,u,n) fused GEMM 128x175x128 + relative shift ----
// LDS: K_ext bf16 [176 rows][128] XOR-swizzled, + bd buffer [128][25] f32
#define KEXT_BYTES (176 * 256)
#define BD_PITCH 25

__global__ __launch_bounds__(512, 4) void k_main(const float* __restrict__ q,
                                                 const float* __restrict__ k,
                                                 const unsigned short* __restrict__ emb,
                                                 float* __restrict__ out) {
    __shared__ __align__(16) char lds_raw[KEXT_BYTES + W_ * BD_PITCH * 4];
    float* bd = (float*)(lds_raw + KEXT_BYTES);

    const int bid = blockIdx.x;
    const int n = bid & 7;
    const int u = (bid >> 3) & 15;
    const int b = bid >> 7;

    const size_t qbase = ((size_t)(b * U_ + u) * W_) * HID + n * HDIM;
    const size_t kbase = ((size_t)(b * U_ + u) * C_) * HID + n * HDIM;
    const size_t obase = ((size_t)((b * NHEADS + n) * U_ + u)) * (W_ * C_);

    const int tid = threadIdx.x;

    // ---- stage K_ext into LDS (convert fp32 -> bf16; rows 151..174 = emb; 175 = 0)
    for (int ui = tid; ui < 176 * 16; ui += 512) {
        const int r = ui >> 4, u16 = ui & 15;
        const int dst = r * 256 + ((u16 * 16) ^ ((r & 7) << 4));
        ushort8v val;
        if (r < C_) {
            const float* src = k + kbase + (size_t)r * HID + u16 * 8;
            float4 f0 = *(const float4*)src;
            float4 f1 = *(const float4*)(src + 4);
            val[0] = f2bf(f0.x); val[1] = f2bf(f0.y); val[2] = f2bf(f0.z); val[3] = f2bf(f0.w);
            val[4] = f2bf(f1.x); val[5] = f2bf(f1.y); val[6] = f2bf(f1.z); val[7] = f2bf(f1.w);
        } else if (r < 175) {
            val = *(const ushort8v*)(emb + (size_t)(r - C_) * HID + n * HDIM + u16 * 8);
        } else {
            val = (ushort8v)(unsigned short)0;
        }
        *(ushort8v*)(lds_raw + dst) = val;
    }
    __syncthreads();

    const int lane = tid & 63;
    const int wave = tid >> 6;      // 0..7, owns rows 16*wave..+15
    const int w0 = wave * 16;
    const int lr = lane & 15;       // fragment row (A) / col (B)
    const int lk = lane >> 4;       // k-group 0..3

    f32x4 acc[11];
    #pragma unroll
    for (int j = 0; j < 11; ++j) acc[j] = (f32x4)(0.f);

    const float* qrow = q + qbase + (size_t)(w0 + lr) * HID + lk * 8;

    #pragma unroll
    for (int kk = 0; kk < 4; ++kk) {
        float4 a0 = *(const float4*)(qrow + kk * 32);
        float4 a1 = *(const float4*)(qrow + kk * 32 + 4);
        ushort8v au;
        au[0] = f2bf(a0.x); au[1] = f2bf(a0.y); au[2] = f2bf(a0.z); au[3] = f2bf(a0.w);
        au[4] = f2bf(a1.x); au[5] = f2bf(a1.y); au[6] = f2bf(a1.z); au[7] = f2bf(a1.w);
        bf16x8 af = __builtin_bit_cast(bf16x8, au);
        #pragma unroll
        for (int j = 0; j < 11; ++j) {
            const int r = j * 16 + lr;
            const int byt = r * 256 + (((kk * 64) + (lk * 16)) ^ ((r & 7) << 4));
            bf16x8 bf = __builtin_bit_cast(bf16x8, *(const ushort8v*)(lds_raw + byt));
            acc[j] = __builtin_amdgcn_mfma_f32_16x16x32_bf16(af, bf, acc[j], 0, 0, 0);
        }
    }

    // ---- write bd columns (S cols 151..174 -> f = 0..23) to LDS
    {
        const int c9 = 144 + lr;              // tile 9: cols 144..159
        if (c9 >= C_) {
            const int f = c9 - C_;            // 0..8
            #pragma unroll
            for (int reg = 0; reg < 4; ++reg) {
                const int w = w0 + lk * 4 + reg;
                bd[w * BD_PITCH + f] = acc[9][reg];
            }
        }
        const int f10 = 9 + lr;               // tile 10: f = 9..24
        if (f10 < SPAN) {
            #pragma unroll
            for (int reg = 0; reg < 4; ++reg) {
                const int w = w0 + lk * 4 + reg;
                bd[w * BD_PITCH + f10] = acc[10][reg];
            }
        }
    }
    __syncthreads();

    // ---- final write: out[w][c] = ac + (0 <= c-w < 24 ? bd[w][c-w] : 0)
    #pragma unroll
    for (int j = 0; j < 10; ++j) {
        const int c = j * 16 + lr;
        if (c < C_) {
            #pragma unroll
            for (int reg = 0; reg < 4; ++reg) {
                const int w = w0 + lk * 4 + reg;
                float v = acc[j][reg];
                const int d = c - w;
                if (d >= 0 && d < SPAN) v += bd[w * BD_PITCH + d];
                out[obase + (size_t)w * C_ + c] = v;
            }
        }
    }
}

extern "C" void kernel_launch(void* const* d_in, const int* in_sizes, int n_in,
                              void* d_out, int out_size, void* d_ws, size_t ws_size,
                              hipStream_t stream) {
    const float* queries = (const float*)d_in[0];
    const float* keys    = (const float*)d_in[1];
    const float* posproj = (const float*)d_in[2];
    float* out = (float*)d_out;

    float* part = (float*)d_ws;                               // 64*1024 f32 = 256 KB
    unsigned short* emb = (unsigned short*)((char*)d_ws + 64 * HID * 4); // 24*1024 bf16

    SC sc;
    for (int f = 0; f < SPAN; ++f) {
        float p = (float)(11 - f);       // MAX_BACKWARD..-MAX_FORWARD
        sc.s[f] = sinf(p);
        sc.c[f] = cosf(p);
    }

    k_partial<<<64, 256, 0, stream>>>(posproj, part);
    k_emb<<<4, 256, 0, stream>>>(part, emb, sc);
    k_main<<<1024, 512, 0, stream>>>(queries, keys, emb, out);
}